// Round 1
// baseline (544.140 us; speedup 1.0000x reference)
//
#include <hip/hip_runtime.h>

typedef __attribute__((ext_vector_type(8))) short bf16x8;
typedef __attribute__((ext_vector_type(4))) float f32x4;
typedef __attribute__((ext_vector_type(8))) unsigned short u16x8;

#define TT 2048

__device__ __forceinline__ unsigned short f2bf(float f) {
  unsigned int u = __builtin_bit_cast(unsigned int, f);
  u += 0x7FFFu + ((u >> 16) & 1u);
  return (unsigned short)(u >> 16);
}

__device__ __forceinline__ void gld16(const void* g, void* l) {
  __builtin_amdgcn_global_load_lds((const __attribute__((address_space(1))) void*)g,
                                   (__attribute__((address_space(3))) void*)l, 16, 0, 0);
}

// ---- convert x (fp32, [8192][2048], first 1024 cols) -> xb bf16 [8192][1024]
__global__ __launch_bounds__(256) void conv_x(const float* __restrict__ x,
                                              unsigned short* __restrict__ xb) {
  const size_t idx = ((size_t)blockIdx.x * 256 + threadIdx.x) * 8;
  const int m = (int)(idx >> 10);
  const int e = (int)(idx & 1023);
  const float4* s = (const float4*)(x + (size_t)m * 2048 + e);
  float4 a = s[0], b = s[1];
  u16x8 v;
  v[0]=f2bf(a.x); v[1]=f2bf(a.y); v[2]=f2bf(a.z); v[3]=f2bf(a.w);
  v[4]=f2bf(b.x); v[5]=f2bf(b.y); v[6]=f2bf(b.z); v[7]=f2bf(b.w);
  *(u16x8*)(xb + idx) = v;
}

// ---- pack Wq/Wk/Wv (fp32 [16][128][2048], first 64/1024 used) -> wb bf16 [3072][1024]
__global__ __launch_bounds__(256) void conv_w(const float* __restrict__ Wq,
                                              const float* __restrict__ Wk,
                                              const float* __restrict__ Wv,
                                              unsigned short* __restrict__ wb) {
  const size_t idx = ((size_t)blockIdx.x * 256 + threadIdx.x) * 8;
  const int n = (int)(idx >> 10);
  const int e = (int)(idx & 1023);
  const int mat = n >> 10, hh = (n >> 6) & 15, d = n & 63;
  const float* W = (mat == 0) ? Wq : ((mat == 1) ? Wk : Wv);
  const float4* s = (const float4*)(W + ((size_t)hh * 128 + d) * 2048 + e);
  float4 a = s[0], b = s[1];
  u16x8 v;
  v[0]=f2bf(a.x); v[1]=f2bf(a.y); v[2]=f2bf(a.z); v[3]=f2bf(a.w);
  v[4]=f2bf(b.x); v[5]=f2bf(b.y); v[6]=f2bf(b.z); v[7]=f2bf(b.w);
  *(u16x8*)(wb + idx) = v;
}

// ---- GEMM: [8192 x 1024] (xb) x [3072 x 1024]^T (wb) -> Q,K [b,h,t,64] bf16, Vt [b,h,64,t] bf16
__global__ __launch_bounds__(256) void qkv_gemm(const unsigned short* __restrict__ xb,
                                                const unsigned short* __restrict__ wb,
                                                unsigned short* __restrict__ Q,
                                                unsigned short* __restrict__ Kt,
                                                unsigned short* __restrict__ Vt) {
  __shared__ unsigned short As[128 * 64];
  __shared__ unsigned short Bs[128 * 64];
  const int tid = threadIdx.x;
  const int w = tid >> 6, lane = tid & 63, g = lane >> 4, c = lane & 15;
  const int m0 = blockIdx.x * 128;
  const int n0 = blockIdx.y * 128;

  f32x4 acc[2][8];
#pragma unroll
  for (int mi = 0; mi < 2; ++mi)
#pragma unroll
    for (int ni = 0; ni < 8; ++ni) acc[mi][ni] = (f32x4){0.f, 0.f, 0.f, 0.f};

  for (int kt = 0; kt < 16; ++kt) {
    const int k0 = kt * 64;
#pragma unroll
    for (int it = 0; it < 4; ++it) {
      int o = (it * 256 + tid) * 16;           // byte offset in 16KB tile
      int r = o >> 7, c2 = o & 127;
      int c2s = c2 ^ ((r & 7) << 4);           // inverse-swizzled source (T2 / rule 21)
      gld16(xb + ((size_t)(m0 + r) * 1024 + k0 + (c2s >> 1)), (char*)As + o);
      gld16(wb + ((size_t)(n0 + r) * 1024 + k0 + (c2s >> 1)), (char*)Bs + o);
    }
    __syncthreads();
#pragma unroll
    for (int kk = 0; kk < 2; ++kk) {
      bf16x8 af[2], bfr[8];
#pragma unroll
      for (int mi = 0; mi < 2; ++mi) {
        int r = w * 32 + mi * 16 + c;
        int c2s = (kk * 64 + g * 16) ^ ((r & 7) << 4);
        af[mi] = *(const bf16x8*)&As[r * 64 + (c2s >> 1)];
      }
#pragma unroll
      for (int ni = 0; ni < 8; ++ni) {
        int r = ni * 16 + c;
        int c2s = (kk * 64 + g * 16) ^ ((r & 7) << 4);
        bfr[ni] = *(const bf16x8*)&Bs[r * 64 + (c2s >> 1)];
      }
#pragma unroll
      for (int mi = 0; mi < 2; ++mi)
#pragma unroll
        for (int ni = 0; ni < 8; ++ni)
          acc[mi][ni] = __builtin_amdgcn_mfma_f32_16x16x32_bf16(af[mi], bfr[ni], acc[mi][ni], 0, 0, 0);
    }
    __syncthreads();
  }

  // epilogue: C[row=(lane>>4)*4+i, col=lane&15]
#pragma unroll
  for (int mi = 0; mi < 2; ++mi) {
    const int row_l = w * 32 + mi * 16 + g * 4;
#pragma unroll
    for (int i = 0; i < 4; ++i) {
      const int m = m0 + row_l + i;
      const int b = m >> 11, t = m & 2047;
#pragma unroll
      for (int ni = 0; ni < 8; ++ni) {
        const int n = n0 + ni * 16 + c;
        const int mat = n >> 10, hh = (n >> 6) & 15, d = n & 63;
        const unsigned short v = f2bf(acc[mi][ni][i]);
        const size_t bh = (size_t)(b * 16 + hh);
        if (mat == 0)      Q [(bh * TT + t) * 64 + d] = v;
        else if (mat == 1) Kt[(bh * TT + t) * 64 + d] = v;
        else               Vt[(bh * 64 + d) * TT + t] = v;
      }
    }
  }
}

// ---- flash attention, causal. 4 waves/block, 16 q-rows/wave, KT=32.
__global__ __launch_bounds__(256) void attn(const unsigned short* __restrict__ Q,
                                            const unsigned short* __restrict__ K,
                                            const unsigned short* __restrict__ Vt,
                                            float* __restrict__ out) {
  __shared__ unsigned short p_lds[4][16][40];   // per-wave P transpose buffer (padded)
  const int blk = blockIdx.x;                   // 4*16*32 = 2048
  const int q0 = (blk & 31) * 64;
  const int h  = (blk >> 5) & 15;
  const int b  = blk >> 9;
  const int tid = threadIdx.x;
  const int w = tid >> 6, lane = tid & 63, g = lane >> 4, c = lane & 15;
  const int qb = q0 + 16 * w;
  const size_t bh = (size_t)(b * 16 + h);
  const unsigned short* Qp = Q  + bh * TT * 64;
  const unsigned short* Kp = K  + bh * TT * 64;
  const unsigned short* Vp = Vt + bh * 64 * TT;

  bf16x8 qf[2];
#pragma unroll
  for (int kk = 0; kk < 2; ++kk)
    qf[kk] = *(const bf16x8*)(Qp + (size_t)(qb + c) * 64 + kk * 32 + g * 8);

  f32x4 o[4];
#pragma unroll
  for (int ni = 0; ni < 4; ++ni) o[ni] = (f32x4){0.f, 0.f, 0.f, 0.f};
  float mi_[4], li_[4];
#pragma unroll
  for (int i = 0; i < 4; ++i) { mi_[i] = -INFINITY; li_[i] = 0.f; }

  const float scale = 0.125f;
  const int nkt = (qb + 47) >> 5;
  for (int kt = 0; kt < nkt; ++kt) {
    const int ks = kt * 32;
    const bool full = (ks + 31) <= qb;

    f32x4 s0 = (f32x4){0.f,0.f,0.f,0.f}, s1 = (f32x4){0.f,0.f,0.f,0.f};
#pragma unroll
    for (int kk = 0; kk < 2; ++kk) {
      bf16x8 k0f = *(const bf16x8*)(Kp + (size_t)(ks + c) * 64 + kk * 32 + g * 8);
      bf16x8 k1f = *(const bf16x8*)(Kp + (size_t)(ks + 16 + c) * 64 + kk * 32 + g * 8);
      s0 = __builtin_amdgcn_mfma_f32_16x16x32_bf16(qf[kk], k0f, s0, 0, 0, 0);
      s1 = __builtin_amdgcn_mfma_f32_16x16x32_bf16(qf[kk], k1f, s1, 0, 0, 0);
    }

#pragma unroll
    for (int i = 0; i < 4; ++i) {
      const int q = qb + g * 4 + i;
      float v0 = s0[i] * scale, v1 = s1[i] * scale;
      const bool ok0 = full || ((ks + c) <= q);
      const bool ok1 = full || ((ks + 16 + c) <= q);
      v0 = ok0 ? v0 : -INFINITY;
      v1 = ok1 ? v1 : -INFINITY;
      float t = fmaxf(v0, v1);
#pragma unroll
      for (int off = 1; off < 16; off <<= 1) t = fmaxf(t, __shfl_xor(t, off));
      const float mnew = fmaxf(mi_[i], t);
      const float alpha = __expf(mi_[i] - mnew);
      const float p0 = ok0 ? __expf(v0 - mnew) : 0.f;
      const float p1 = ok1 ? __expf(v1 - mnew) : 0.f;
      float rs = p0 + p1;
#pragma unroll
      for (int off = 1; off < 16; off <<= 1) rs += __shfl_xor(rs, off);
      li_[i] = li_[i] * alpha + rs;
      mi_[i] = mnew;
#pragma unroll
      for (int ni = 0; ni < 4; ++ni) o[ni][i] *= alpha;
      p_lds[w][g * 4 + i][c]      = f2bf(p0);
      p_lds[w][g * 4 + i][16 + c] = f2bf(p1);
    }
    asm volatile("s_waitcnt lgkmcnt(0)" ::: "memory");
    __builtin_amdgcn_sched_barrier(0);
    bf16x8 pf = *(const bf16x8*)&p_lds[w][c][g * 8];
#pragma unroll
    for (int ni = 0; ni < 4; ++ni) {
      bf16x8 vf = *(const bf16x8*)(Vp + (size_t)(ni * 16 + c) * TT + ks + g * 8);
      o[ni] = __builtin_amdgcn_mfma_f32_16x16x32_bf16(pf, vf, o[ni], 0, 0, 0);
    }
  }

  // store O / l
#pragma unroll
  for (int i = 0; i < 4; ++i) {
    const int tq = qb + g * 4 + i;
    const float inv = 1.f / li_[i];
#pragma unroll
    for (int ni = 0; ni < 4; ++ni)
      out[((size_t)(b * TT + tq)) * 2048 + h * 64 + ni * 16 + c] = o[ni][i] * inv;
  }

  // zero the pad: rows q0..q0+63, cols 1024+h*64 .. +63
  const float4 z = make_float4(0.f, 0.f, 0.f, 0.f);
#pragma unroll
  for (int it = 0; it < 4; ++it) {
    const int o_ = it * 256 + tid;
    const int r = o_ >> 4, cc = o_ & 15;
    *((float4*)(out + ((size_t)(b * TT + q0 + r)) * 2048 + 1024 + h * 64) + cc) = z;
  }
}

extern "C" void kernel_launch(void* const* d_in, const int* in_sizes, int n_in,
                              void* d_out, int out_size, void* d_ws, size_t ws_size,
                              hipStream_t stream) {
  const float* x  = (const float*)d_in[0];
  const float* Wq = (const float*)d_in[1];
  const float* Wk = (const float*)d_in[2];
  const float* Wv = (const float*)d_in[3];

  unsigned short* wsp = (unsigned short*)d_ws;
  unsigned short* Q   = wsp;                       // 8,388,608 bf16
  unsigned short* Kt  = wsp + (size_t)8388608;     // 8,388,608 bf16
  unsigned short* Vt  = wsp + (size_t)16777216;    // 8,388,608 bf16

  // d_out doubles as scratch for the bf16-converted inputs; fully overwritten later.
  unsigned short* xb = (unsigned short*)d_out;                          // 16.8 MB
  unsigned short* wb = (unsigned short*)((char*)d_out + 33554432);      // 6.3 MB
  float* out = (float*)d_out;

  conv_x<<<4096, 256, 0, stream>>>(x, xb);
  conv_w<<<1536, 256, 0, stream>>>(Wq, Wk, Wv, wb);
  qkv_gemm<<<dim3(64, 24), 256, 0, stream>>>(xb, wb, Q, Kt, Vt);
  attn<<<2048, 256, 0, stream>>>(Q, Kt, Vt, out);
}

// Round 2
// 240.681 us; speedup vs baseline: 2.2608x; 2.2608x over previous
//
#include <hip/hip_runtime.h>

typedef __attribute__((ext_vector_type(8))) short bf16x8;
typedef __attribute__((ext_vector_type(4))) float f32x4;
typedef __attribute__((ext_vector_type(16))) float f32x16;
typedef __attribute__((ext_vector_type(8))) unsigned short u16x8;
typedef __attribute__((ext_vector_type(4))) unsigned int u32x4;

#define TT 2048

__device__ __forceinline__ unsigned short f2bf(float f) {
  unsigned int u = __builtin_bit_cast(unsigned int, f);
  u += 0x7FFFu + ((u >> 16) & 1u);
  return (unsigned short)(u >> 16);
}

__device__ __forceinline__ void gld16(const void* g, void* l) {
  __builtin_amdgcn_global_load_lds((const __attribute__((address_space(1))) void*)g,
                                   (__attribute__((address_space(3))) void*)l, 16, 0, 0);
}

__device__ __forceinline__ unsigned int cvtpk(float lo, float hi) {
  unsigned int r;
  asm("v_cvt_pk_bf16_f32 %0, %1, %2" : "=v"(r) : "v"(lo), "v"(hi));
  return r;
}

__device__ __forceinline__ void pl32swap(unsigned int& a, unsigned int& b) {
  asm volatile("v_permlane32_swap_b32 %0, %1" : "+v"(a), "+v"(b));
}

// ---- convert x (fp32, [8192][2048], first 1024 cols) -> xb bf16 [8192][1024]
__global__ __launch_bounds__(256) void conv_x(const float* __restrict__ x,
                                              unsigned short* __restrict__ xb) {
  const size_t idx = ((size_t)blockIdx.x * 256 + threadIdx.x) * 8;
  const int m = (int)(idx >> 10);
  const int e = (int)(idx & 1023);
  const float4* s = (const float4*)(x + (size_t)m * 2048 + e);
  float4 a = s[0], b = s[1];
  u16x8 v;
  v[0]=f2bf(a.x); v[1]=f2bf(a.y); v[2]=f2bf(a.z); v[3]=f2bf(a.w);
  v[4]=f2bf(b.x); v[5]=f2bf(b.y); v[6]=f2bf(b.z); v[7]=f2bf(b.w);
  *(u16x8*)(xb + idx) = v;
}

// ---- pack Wq/Wk/Wv (fp32 [16][128][2048], first 64/1024 used) -> wb bf16 [3072][1024]
__global__ __launch_bounds__(256) void conv_w(const float* __restrict__ Wq,
                                              const float* __restrict__ Wk,
                                              const float* __restrict__ Wv,
                                              unsigned short* __restrict__ wb) {
  const size_t idx = ((size_t)blockIdx.x * 256 + threadIdx.x) * 8;
  const int n = (int)(idx >> 10);
  const int e = (int)(idx & 1023);
  const int mat = n >> 10, hh = (n >> 6) & 15, d = n & 63;
  const float* W = (mat == 0) ? Wq : ((mat == 1) ? Wk : Wv);
  const float4* s = (const float4*)(W + ((size_t)hh * 128 + d) * 2048 + e);
  float4 a = s[0], b = s[1];
  u16x8 v;
  v[0]=f2bf(a.x); v[1]=f2bf(a.y); v[2]=f2bf(a.z); v[3]=f2bf(a.w);
  v[4]=f2bf(b.x); v[5]=f2bf(b.y); v[6]=f2bf(b.z); v[7]=f2bf(b.w);
  *(u16x8*)(wb + idx) = v;
}

// ---- GEMM: [8192 x 1024] (xb) x [3072 x 1024]^T (wb) -> Q,K [b,h,t,64] bf16, Vt [b,h,64,t] bf16
__global__ __launch_bounds__(256) void qkv_gemm(const unsigned short* __restrict__ xb,
                                                const unsigned short* __restrict__ wb,
                                                unsigned short* __restrict__ Q,
                                                unsigned short* __restrict__ Kt,
                                                unsigned short* __restrict__ Vt) {
  __shared__ unsigned short As[128 * 64];
  __shared__ unsigned short Bs[128 * 64];
  const int tid = threadIdx.x;
  const int w = tid >> 6, lane = tid & 63, g = lane >> 4, c = lane & 15;
  const int m0 = blockIdx.x * 128;
  const int n0 = blockIdx.y * 128;

  f32x4 acc[2][8];
#pragma unroll
  for (int mi = 0; mi < 2; ++mi)
#pragma unroll
    for (int ni = 0; ni < 8; ++ni) acc[mi][ni] = (f32x4){0.f, 0.f, 0.f, 0.f};

  for (int kt = 0; kt < 16; ++kt) {
    const int k0 = kt * 64;
#pragma unroll
    for (int it = 0; it < 4; ++it) {
      int o = (it * 256 + tid) * 16;           // byte offset in 16KB tile
      int r = o >> 7, c2 = o & 127;
      int c2s = c2 ^ ((r & 7) << 4);           // inverse-swizzled source
      gld16(xb + ((size_t)(m0 + r) * 1024 + k0 + (c2s >> 1)), (char*)As + o);
      gld16(wb + ((size_t)(n0 + r) * 1024 + k0 + (c2s >> 1)), (char*)Bs + o);
    }
    __syncthreads();
#pragma unroll
    for (int kk = 0; kk < 2; ++kk) {
      bf16x8 af[2], bfr[8];
#pragma unroll
      for (int mi = 0; mi < 2; ++mi) {
        int r = w * 32 + mi * 16 + c;
        int c2s = (kk * 64 + g * 16) ^ ((r & 7) << 4);
        af[mi] = *(const bf16x8*)&As[r * 64 + (c2s >> 1)];
      }
#pragma unroll
      for (int ni = 0; ni < 8; ++ni) {
        int r = ni * 16 + c;
        int c2s = (kk * 64 + g * 16) ^ ((r & 7) << 4);
        bfr[ni] = *(const bf16x8*)&Bs[r * 64 + (c2s >> 1)];
      }
#pragma unroll
      for (int mi = 0; mi < 2; ++mi)
#pragma unroll
        for (int ni = 0; ni < 8; ++ni)
          acc[mi][ni] = __builtin_amdgcn_mfma_f32_16x16x32_bf16(af[mi], bfr[ni], acc[mi][ni], 0, 0, 0);
    }
    __syncthreads();
  }

  // epilogue: C[row=(lane>>4)*4+i, col=lane&15]
#pragma unroll
  for (int mi = 0; mi < 2; ++mi) {
    const int row_l = w * 32 + mi * 16 + g * 4;
#pragma unroll
    for (int i = 0; i < 4; ++i) {
      const int m = m0 + row_l + i;
      const int b = m >> 11, t = m & 2047;
#pragma unroll
      for (int ni = 0; ni < 8; ++ni) {
        const int n = n0 + ni * 16 + c;
        const int mat = n >> 10, hh = (n >> 6) & 15, d = n & 63;
        const unsigned short v = f2bf(acc[mi][ni][i]);
        const size_t bh = (size_t)(b * 16 + hh);
        if (mat == 0)      Q [(bh * TT + t) * 64 + d] = v;
        else if (mat == 1) Kt[(bh * TT + t) * 64 + d] = v;
        else               Vt[(bh * 64 + d) * TT + t] = v;
      }
    }
  }
}

// ---- zero pad cols 1024..2047 of out (runs after gemm consumed xb scratch)
__global__ __launch_bounds__(256) void zero_pad(float* __restrict__ out) {
  const int idx = blockIdx.x * 256 + threadIdx.x;     // 8192*256
  const int row = idx >> 8, c4 = idx & 255;
  *((float4*)(out + (size_t)row * 2048 + 1024) + c4) = make_float4(0.f, 0.f, 0.f, 0.f);
}

// ---- flash attention, causal. 4 waves/block, 32 q-rows/wave, KVBLK=32.
// Swapped layout: S^T = mfma(K, Q) so each lane owns q=lane&31; O^T = mfma(Vt, P^T).
__global__ __launch_bounds__(256) void attn2(const unsigned short* __restrict__ Q,
                                             const unsigned short* __restrict__ K,
                                             const unsigned short* __restrict__ Vt,
                                             float* __restrict__ out) {
  const int blk = blockIdx.x;            // 1024
  const int bh = blk & 63;               // bh%8 == blk%8 -> per-XCD L2 holds 8 heads
  const int qi = 15 - (blk >> 6);        // heavy (high-q) blocks first
  const int b = bh >> 4, h = bh & 15;
  const int tid = threadIdx.x;
  const int w = tid >> 6, lane = tid & 63;
  const int ql = lane & 31;
  const int hi = lane >> 5, hi8 = (lane >> 5) * 8;
  const int qb = qi * 128 + w * 32;
  const int q = qb + ql;
  const unsigned short* Qp = Q  + (size_t)bh * TT * 64;
  const unsigned short* Kp = K  + (size_t)bh * TT * 64;
  const unsigned short* Vp = Vt + (size_t)bh * 64 * TT;

  bf16x8 qf[4];
#pragma unroll
  for (int c = 0; c < 4; ++c)
    qf[c] = *(const bf16x8*)(Qp + (size_t)q * 64 + c * 16 + hi8);

  f32x16 o0, o1;
#pragma unroll
  for (int r = 0; r < 16; ++r) { o0[r] = 0.f; o1[r] = 0.f; }
  float m = -3.0e38f, l = 0.f;
  const float c2 = 0.125f * 1.44269504f;

  const int nkt = qb / 32 + 1;
  for (int kt = 0; kt < nkt; ++kt) {
    const int ks = kt * 32;

    // --- QK^T swapped: st[r] = S^T[k=(r&3)+8*(r>>2)+4*hi][q=ql]
    const unsigned short* kb = Kp + (size_t)(ks + ql) * 64 + hi8;
    bf16x8 kf0 = *(const bf16x8*)(kb);
    bf16x8 kf1 = *(const bf16x8*)(kb + 16);
    bf16x8 kf2 = *(const bf16x8*)(kb + 32);
    bf16x8 kf3 = *(const bf16x8*)(kb + 48);
    f32x16 st;
#pragma unroll
    for (int r = 0; r < 16; ++r) st[r] = 0.f;
    __builtin_amdgcn_s_setprio(1);
    st = __builtin_amdgcn_mfma_f32_32x32x16_bf16(kf0, qf[0], st, 0, 0, 0);
    st = __builtin_amdgcn_mfma_f32_32x32x16_bf16(kf1, qf[1], st, 0, 0, 0);
    st = __builtin_amdgcn_mfma_f32_32x32x16_bf16(kf2, qf[2], st, 0, 0, 0);
    st = __builtin_amdgcn_mfma_f32_32x32x16_bf16(kf3, qf[3], st, 0, 0, 0);
    __builtin_amdgcn_s_setprio(0);

    // --- causal mask (only the diagonal tile)
    if (ks == qb) {
#pragma unroll
      for (int r = 0; r < 16; ++r) {
        const int krow = (r & 3) + 8 * (r >> 2) + 4 * hi;
        if (krow > ql) st[r] = -3.0e38f;
      }
    }

    // --- online softmax, fully in-register (lane owns q=ql)
    float pm = st[0];
#pragma unroll
    for (int r = 1; r < 16; ++r) pm = fmaxf(pm, st[r]);
    pm = fmaxf(pm, __shfl_xor(pm, 32));
    if (!__all(pm - m <= 44.36f)) {            // defer-max (THR=8 in exp units)
      const float mnew = fmaxf(m, pm);
      const float alpha = __builtin_amdgcn_exp2f((m - mnew) * c2);
      m = mnew;
      l *= alpha;
#pragma unroll
      for (int r = 0; r < 16; ++r) { o0[r] *= alpha; o1[r] *= alpha; }
    }
    float p[16];
    float rs = 0.f;
#pragma unroll
    for (int r = 0; r < 16; ++r) {
      p[r] = __builtin_amdgcn_exp2f((st[r] - m) * c2);
      rs += p[r];
    }
    rs += __shfl_xor(rs, 32);
    l += rs;

    // --- pack P^T into B-fragments: cvt_pk + permlane32_swap (T12)
    unsigned int a0 = cvtpk(p[0], p[1]),  a1 = cvtpk(p[2], p[3]);
    unsigned int b0 = cvtpk(p[4], p[5]),  b1 = cvtpk(p[6], p[7]);
    pl32swap(a0, b0); pl32swap(a1, b1);
    unsigned int c0 = cvtpk(p[8], p[9]),  c1 = cvtpk(p[10], p[11]);
    unsigned int d0 = cvtpk(p[12], p[13]), d1 = cvtpk(p[14], p[15]);
    pl32swap(c0, d0); pl32swap(c1, d1);
    u32x4 pw0 = {a0, a1, b0, b1};
    u32x4 pw1 = {c0, c1, d0, d1};
    bf16x8 pf0 = __builtin_bit_cast(bf16x8, pw0);
    bf16x8 pf1 = __builtin_bit_cast(bf16x8, pw1);

    // --- PV swapped: O^T[d][q] += V^T[d][k] * P^T[k][q]
    const unsigned short* vb = Vp + (size_t)ql * TT + ks + hi8;
    bf16x8 v00 = *(const bf16x8*)(vb);
    bf16x8 v01 = *(const bf16x8*)(vb + 16);
    bf16x8 v10 = *(const bf16x8*)(vb + 32 * TT);
    bf16x8 v11 = *(const bf16x8*)(vb + 32 * TT + 16);
    __builtin_amdgcn_s_setprio(1);
    o0 = __builtin_amdgcn_mfma_f32_32x32x16_bf16(v00, pf0, o0, 0, 0, 0);
    o0 = __builtin_amdgcn_mfma_f32_32x32x16_bf16(v01, pf1, o0, 0, 0, 0);
    o1 = __builtin_amdgcn_mfma_f32_32x32x16_bf16(v10, pf0, o1, 0, 0, 0);
    o1 = __builtin_amdgcn_mfma_f32_32x32x16_bf16(v11, pf1, o1, 0, 0, 0);
    __builtin_amdgcn_s_setprio(0);
  }

  const float inv = 1.f / l;
  float* ob = out + ((size_t)b * TT + q) * 2048 + h * 64;
#pragma unroll
  for (int r = 0; r < 16; ++r) {
    const int row = (r & 3) + 8 * (r >> 2) + 4 * hi;
    ob[row]      = o0[r] * inv;
    ob[32 + row] = o1[r] * inv;
  }
}

extern "C" void kernel_launch(void* const* d_in, const int* in_sizes, int n_in,
                              void* d_out, int out_size, void* d_ws, size_t ws_size,
                              hipStream_t stream) {
  const float* x  = (const float*)d_in[0];
  const float* Wq = (const float*)d_in[1];
  const float* Wk = (const float*)d_in[2];
  const float* Wv = (const float*)d_in[3];

  unsigned short* wsp = (unsigned short*)d_ws;
  unsigned short* Q   = wsp;                       // 8,388,608 bf16
  unsigned short* Kt  = wsp + (size_t)8388608;
  unsigned short* Vt  = wsp + (size_t)16777216;

  // d_out doubles as scratch for bf16-converted inputs; fully overwritten later.
  unsigned short* xb = (unsigned short*)d_out;                          // 16.8 MB
  unsigned short* wb = (unsigned short*)((char*)d_out + 33554432);      // 6.3 MB
  float* out = (float*)d_out;

  conv_x<<<4096, 256, 0, stream>>>(x, xb);
  conv_w<<<1536, 256, 0, stream>>>(Wq, Wk, Wv, wb);
  qkv_gemm<<<dim3(64, 24), 256, 0, stream>>>(xb, wb, Q, Kt, Vt);
  zero_pad<<<8192, 256, 0, stream>>>(out);
  attn2<<<1024, 256, 0, stream>>>(Q, Kt, Vt, out);
}

// Round 3
// 230.418 us; speedup vs baseline: 2.3615x; 1.0445x over previous
//
#include <hip/hip_runtime.h>

typedef __attribute__((ext_vector_type(8))) short bf16x8;
typedef __attribute__((ext_vector_type(4))) float f32x4;
typedef __attribute__((ext_vector_type(16))) float f32x16;
typedef __attribute__((ext_vector_type(8))) unsigned short u16x8;
typedef __attribute__((ext_vector_type(4))) unsigned int u32x4;

#define TT 2048

__device__ __forceinline__ unsigned short f2bf(float f) {
  unsigned int u = __builtin_bit_cast(unsigned int, f);
  u += 0x7FFFu + ((u >> 16) & 1u);
  return (unsigned short)(u >> 16);
}

__device__ __forceinline__ void gld16(const void* g, void* l) {
  __builtin_amdgcn_global_load_lds((const __attribute__((address_space(1))) void*)g,
                                   (__attribute__((address_space(3))) void*)l, 16, 0, 0);
}

__device__ __forceinline__ unsigned int cvtpk(float lo, float hi) {
  unsigned int r;
  asm("v_cvt_pk_bf16_f32 %0, %1, %2" : "=v"(r) : "v"(lo), "v"(hi));
  return r;
}

__device__ __forceinline__ void pl32swap(unsigned int& a, unsigned int& b) {
  asm volatile("v_permlane32_swap_b32 %0, %1" : "+v"(a), "+v"(b));
}

// ---- convert x (fp32, [8192][2048], first 1024 cols) -> xb bf16 [8192][1024]
__global__ __launch_bounds__(256) void conv_x(const float* __restrict__ x,
                                              unsigned short* __restrict__ xb) {
  const size_t idx = ((size_t)blockIdx.x * 256 + threadIdx.x) * 8;
  const int m = (int)(idx >> 10);
  const int e = (int)(idx & 1023);
  const float4* s = (const float4*)(x + (size_t)m * 2048 + e);
  float4 a = s[0], b = s[1];
  u16x8 v;
  v[0]=f2bf(a.x); v[1]=f2bf(a.y); v[2]=f2bf(a.z); v[3]=f2bf(a.w);
  v[4]=f2bf(b.x); v[5]=f2bf(b.y); v[6]=f2bf(b.z); v[7]=f2bf(b.w);
  *(u16x8*)(xb + idx) = v;
}

// ---- pack Wq/Wk/Wv (fp32 [16][128][2048], first 64/1024 used) -> wb bf16 [3072][1024]
__global__ __launch_bounds__(256) void conv_w(const float* __restrict__ Wq,
                                              const float* __restrict__ Wk,
                                              const float* __restrict__ Wv,
                                              unsigned short* __restrict__ wb) {
  const size_t idx = ((size_t)blockIdx.x * 256 + threadIdx.x) * 8;
  const int n = (int)(idx >> 10);
  const int e = (int)(idx & 1023);
  const int mat = n >> 10, hh = (n >> 6) & 15, d = n & 63;
  const float* W = (mat == 0) ? Wq : ((mat == 1) ? Wk : Wv);
  const float4* s = (const float4*)(W + ((size_t)hh * 128 + d) * 2048 + e);
  float4 a = s[0], b = s[1];
  u16x8 v;
  v[0]=f2bf(a.x); v[1]=f2bf(a.y); v[2]=f2bf(a.z); v[3]=f2bf(a.w);
  v[4]=f2bf(b.x); v[5]=f2bf(b.y); v[6]=f2bf(b.z); v[7]=f2bf(b.w);
  *(u16x8*)(wb + idx) = v;
}

// ---- GEMM: [8192 x 1024] (xb) x [3072 x 1024]^T (wb) -> Q,K [b,h,t,64] bf16, Vt [b,h,64,t] bf16
__global__ __launch_bounds__(256) void qkv_gemm(const unsigned short* __restrict__ xb,
                                                const unsigned short* __restrict__ wb,
                                                unsigned short* __restrict__ Q,
                                                unsigned short* __restrict__ Kt,
                                                unsigned short* __restrict__ Vt) {
  __shared__ unsigned short As[128 * 64];
  __shared__ unsigned short Bs[128 * 64];
  const int tid = threadIdx.x;
  const int w = tid >> 6, lane = tid & 63, g = lane >> 4, c = lane & 15;
  const int m0 = blockIdx.x * 128;
  const int n0 = blockIdx.y * 128;

  f32x4 acc[2][8];
#pragma unroll
  for (int mi = 0; mi < 2; ++mi)
#pragma unroll
    for (int ni = 0; ni < 8; ++ni) acc[mi][ni] = (f32x4){0.f, 0.f, 0.f, 0.f};

  for (int kt = 0; kt < 16; ++kt) {
    const int k0 = kt * 64;
#pragma unroll
    for (int it = 0; it < 4; ++it) {
      int o = (it * 256 + tid) * 16;           // byte offset in 16KB tile
      int r = o >> 7, c2 = o & 127;
      int c2s = c2 ^ ((r & 7) << 4);           // inverse-swizzled source
      gld16(xb + ((size_t)(m0 + r) * 1024 + k0 + (c2s >> 1)), (char*)As + o);
      gld16(wb + ((size_t)(n0 + r) * 1024 + k0 + (c2s >> 1)), (char*)Bs + o);
    }
    __syncthreads();
#pragma unroll
    for (int kk = 0; kk < 2; ++kk) {
      bf16x8 af[2], bfr[8];
#pragma unroll
      for (int mi = 0; mi < 2; ++mi) {
        int r = w * 32 + mi * 16 + c;
        int c2s = (kk * 64 + g * 16) ^ ((r & 7) << 4);
        af[mi] = *(const bf16x8*)&As[r * 64 + (c2s >> 1)];
      }
#pragma unroll
      for (int ni = 0; ni < 8; ++ni) {
        int r = ni * 16 + c;
        int c2s = (kk * 64 + g * 16) ^ ((r & 7) << 4);
        bfr[ni] = *(const bf16x8*)&Bs[r * 64 + (c2s >> 1)];
      }
#pragma unroll
      for (int mi = 0; mi < 2; ++mi)
#pragma unroll
        for (int ni = 0; ni < 8; ++ni)
          acc[mi][ni] = __builtin_amdgcn_mfma_f32_16x16x32_bf16(af[mi], bfr[ni], acc[mi][ni], 0, 0, 0);
    }
    __syncthreads();
  }

  // epilogue: C[row=(lane>>4)*4+i, col=lane&15]
#pragma unroll
  for (int mi = 0; mi < 2; ++mi) {
    const int row_l = w * 32 + mi * 16 + g * 4;
#pragma unroll
    for (int i = 0; i < 4; ++i) {
      const int m = m0 + row_l + i;
      const int b = m >> 11, t = m & 2047;
#pragma unroll
      for (int ni = 0; ni < 8; ++ni) {
        const int n = n0 + ni * 16 + c;
        const int mat = n >> 10, hh = (n >> 6) & 15, d = n & 63;
        const unsigned short v = f2bf(acc[mi][ni][i]);
        const size_t bh = (size_t)(b * 16 + hh);
        if (mat == 0)      Q [(bh * TT + t) * 64 + d] = v;
        else if (mat == 1) Kt[(bh * TT + t) * 64 + d] = v;
        else               Vt[(bh * 64 + d) * TT + t] = v;
      }
    }
  }
}

// ---- zero pad cols 1024..2047 of out (runs after gemm consumed xb scratch)
__global__ __launch_bounds__(256) void zero_pad(float* __restrict__ out) {
  const int idx = blockIdx.x * 256 + threadIdx.x;     // 8192*256
  const int row = idx >> 8, c4 = idx & 255;
  *((float4*)(out + (size_t)row * 2048 + 1024) + c4) = make_float4(0.f, 0.f, 0.f, 0.f);
}

// ---- flash attention, causal. 2 waves/block, 32 q-rows/wave, KVBLK=32.
// Swapped layout: S^T = mfma(K, Q); lane owns q = lane&31. O^T = mfma(Vt, P^T).
// K register double-buffered (prefetch t+1); V issue-early/use-late (T14).
__global__ __launch_bounds__(128) void attn3(const unsigned short* __restrict__ Q,
                                             const unsigned short* __restrict__ K,
                                             const unsigned short* __restrict__ Vt,
                                             float* __restrict__ out) {
  const int blk = blockIdx.x;            // 2048
  const int bh = blk & 63;               // bh%8 -> XCD L2 affinity
  const int qi = 31 - (blk >> 6);        // heavy (high-q) blocks first
  const int b = bh >> 4, h = bh & 15;
  const int tid = threadIdx.x;
  const int w = tid >> 6, lane = tid & 63;
  const int ql = lane & 31;
  const int hi = lane >> 5, hi8 = hi * 8;
  const int qb = qi * 64 + w * 32;
  const int q = qb + ql;
  const unsigned short* Qp = Q  + (size_t)bh * TT * 64;
  const unsigned short* Kp = K  + (size_t)bh * TT * 64;
  const unsigned short* Vp = Vt + (size_t)bh * 64 * TT;

  bf16x8 qf0, qf1, qf2, qf3;
  {
    const unsigned short* qa = Qp + (size_t)q * 64 + hi8;
    qf0 = *(const bf16x8*)(qa);
    qf1 = *(const bf16x8*)(qa + 16);
    qf2 = *(const bf16x8*)(qa + 32);
    qf3 = *(const bf16x8*)(qa + 48);
  }

  f32x16 o0, o1;
#pragma unroll
  for (int r = 0; r < 16; ++r) { o0[r] = 0.f; o1[r] = 0.f; }
  float m = -3.0e38f, l = 0.f;
  const float c2 = 0.125f * 1.44269504f;

  const int nkt = qb / 32 + 1;
  int kt = 0;

  // prologue: K(0) -> A set
  bf16x8 kA0, kA1, kA2, kA3, kB0, kB1, kB2, kB3;
  {
    const unsigned short* kb = Kp + (size_t)ql * 64 + hi8;
    kA0 = *(const bf16x8*)(kb);
    kA1 = *(const bf16x8*)(kb + 16);
    kA2 = *(const bf16x8*)(kb + 32);
    kA3 = *(const bf16x8*)(kb + 48);
  }

  auto step = [&](bf16x8& c0, bf16x8& c1, bf16x8& c2x, bf16x8& c3,
                  bf16x8& n0, bf16x8& n1, bf16x8& n2, bf16x8& n3) {
    const int ks = kt * 32;
    // V(t): issue early, used after softmax (~200 cy later)
    const unsigned short* vb = Vp + (size_t)ql * TT + ks + hi8;
    bf16x8 v0 = *(const bf16x8*)(vb);
    bf16x8 v1 = *(const bf16x8*)(vb + 16);
    bf16x8 v2 = *(const bf16x8*)(vb + 32 * TT);
    bf16x8 v3 = *(const bf16x8*)(vb + 32 * TT + 16);
    // K(t+1): prefetch into the other register set
    if (kt + 1 < nkt) {
      const unsigned short* kb = Kp + (size_t)(ks + 32 + ql) * 64 + hi8;
      n0 = *(const bf16x8*)(kb);
      n1 = *(const bf16x8*)(kb + 16);
      n2 = *(const bf16x8*)(kb + 32);
      n3 = *(const bf16x8*)(kb + 48);
    }
    // QK^T swapped: st[r] = S^T[k=(r&3)+8*(r>>2)+4*hi][q=ql]
    f32x16 st;
#pragma unroll
    for (int r = 0; r < 16; ++r) st[r] = 0.f;
    __builtin_amdgcn_s_setprio(1);
    st = __builtin_amdgcn_mfma_f32_32x32x16_bf16(c0, qf0, st, 0, 0, 0);
    st = __builtin_amdgcn_mfma_f32_32x32x16_bf16(c1, qf1, st, 0, 0, 0);
    st = __builtin_amdgcn_mfma_f32_32x32x16_bf16(c2x, qf2, st, 0, 0, 0);
    st = __builtin_amdgcn_mfma_f32_32x32x16_bf16(c3, qf3, st, 0, 0, 0);
    __builtin_amdgcn_s_setprio(0);

    if (ks == qb) {        // diagonal tile: causal mask
#pragma unroll
      for (int r = 0; r < 16; ++r) {
        const int krow = (r & 3) + 8 * (r >> 2) + 4 * hi;
        if (krow > ql) st[r] = -3.0e38f;
      }
    }

    // online softmax, in-register (lane owns q=ql)
    float t0 = fmaxf(st[0], st[1]),  t1 = fmaxf(st[2], st[3]);
    float t2 = fmaxf(st[4], st[5]),  t3 = fmaxf(st[6], st[7]);
    float t4 = fmaxf(st[8], st[9]),  t5 = fmaxf(st[10], st[11]);
    float t6 = fmaxf(st[12], st[13]), t7 = fmaxf(st[14], st[15]);
    t0 = fmaxf(t0, t1); t2 = fmaxf(t2, t3); t4 = fmaxf(t4, t5); t6 = fmaxf(t6, t7);
    float pm = fmaxf(fmaxf(t0, t2), fmaxf(t4, t6));
    pm = fmaxf(pm, __shfl_xor(pm, 32));
    if (!__all(pm - m <= 44.36f)) {            // defer-max
      const float mnew = fmaxf(m, pm);
      const float alpha = __builtin_amdgcn_exp2f((m - mnew) * c2);
      m = mnew;
      l *= alpha;
#pragma unroll
      for (int r = 0; r < 16; ++r) { o0[r] *= alpha; o1[r] *= alpha; }
    }
    float p[16];
    float rs = 0.f;
#pragma unroll
    for (int r = 0; r < 16; ++r) {
      p[r] = __builtin_amdgcn_exp2f((st[r] - m) * c2);
      rs += p[r];
    }
    rs += __shfl_xor(rs, 32);
    l += rs;

    // pack P^T into B-fragments (cvt_pk + permlane32_swap)
    unsigned int a0 = cvtpk(p[0], p[1]),  a1 = cvtpk(p[2], p[3]);
    unsigned int b0 = cvtpk(p[4], p[5]),  b1 = cvtpk(p[6], p[7]);
    pl32swap(a0, b0); pl32swap(a1, b1);
    unsigned int cc0 = cvtpk(p[8], p[9]),  cc1 = cvtpk(p[10], p[11]);
    unsigned int dd0 = cvtpk(p[12], p[13]), dd1 = cvtpk(p[14], p[15]);
    pl32swap(cc0, dd0); pl32swap(cc1, dd1);
    u32x4 pw0 = {a0, a1, b0, b1};
    u32x4 pw1 = {cc0, cc1, dd0, dd1};
    bf16x8 pf0 = __builtin_bit_cast(bf16x8, pw0);
    bf16x8 pf1 = __builtin_bit_cast(bf16x8, pw1);

    // PV swapped: O^T[d][q] += V^T[d][k] * P^T[k][q]
    __builtin_amdgcn_s_setprio(1);
    o0 = __builtin_amdgcn_mfma_f32_32x32x16_bf16(v0, pf0, o0, 0, 0, 0);
    o0 = __builtin_amdgcn_mfma_f32_32x32x16_bf16(v1, pf1, o0, 0, 0, 0);
    o1 = __builtin_amdgcn_mfma_f32_32x32x16_bf16(v2, pf0, o1, 0, 0, 0);
    o1 = __builtin_amdgcn_mfma_f32_32x32x16_bf16(v3, pf1, o1, 0, 0, 0);
    __builtin_amdgcn_s_setprio(0);
  };

  while (true) {
    step(kA0, kA1, kA2, kA3, kB0, kB1, kB2, kB3);
    if (++kt >= nkt) break;
    step(kB0, kB1, kB2, kB3, kA0, kA1, kA2, kA3);
    if (++kt >= nkt) break;
  }

  const float inv = 1.f / l;
  float* ob = out + ((size_t)b * TT + q) * 2048 + h * 64;
#pragma unroll
  for (int r = 0; r < 16; ++r) {
    const int row = (r & 3) + 8 * (r >> 2) + 4 * hi;
    ob[row]      = o0[r] * inv;
    ob[32 + row] = o1[r] * inv;
  }
}

extern "C" void kernel_launch(void* const* d_in, const int* in_sizes, int n_in,
                              void* d_out, int out_size, void* d_ws, size_t ws_size,
                              hipStream_t stream) {
  const float* x  = (const float*)d_in[0];
  const float* Wq = (const float*)d_in[1];
  const float* Wk = (const float*)d_in[2];
  const float* Wv = (const float*)d_in[3];

  unsigned short* wsp = (unsigned short*)d_ws;
  unsigned short* Q   = wsp;                       // 8,388,608 bf16
  unsigned short* Kt  = wsp + (size_t)8388608;
  unsigned short* Vt  = wsp + (size_t)16777216;

  // d_out doubles as scratch for bf16-converted inputs; fully overwritten later.
  unsigned short* xb = (unsigned short*)d_out;                          // 16.8 MB
  unsigned short* wb = (unsigned short*)((char*)d_out + 33554432);      // 6.3 MB
  float* out = (float*)d_out;

  conv_x<<<4096, 256, 0, stream>>>(x, xb);
  conv_w<<<1536, 256, 0, stream>>>(Wq, Wk, Wv, wb);
  qkv_gemm<<<dim3(64, 24), 256, 0, stream>>>(xb, wb, Q, Kt, Vt);
  zero_pad<<<8192, 256, 0, stream>>>(out);
  attn3<<<2048, 128, 0, stream>>>(Q, Kt, Vt, out);
}

// Round 4
// 183.207 us; speedup vs baseline: 2.9701x; 1.2577x over previous
//
#include <hip/hip_runtime.h>

typedef __attribute__((ext_vector_type(8))) short bf16x8;
typedef __attribute__((ext_vector_type(4))) float f32x4;
typedef __attribute__((ext_vector_type(16))) float f32x16;
typedef __attribute__((ext_vector_type(8))) unsigned short u16x8;
typedef __attribute__((ext_vector_type(4))) unsigned int u32x4;

#define TT 2048

__device__ __forceinline__ unsigned short f2bf(float f) {
  unsigned int u = __builtin_bit_cast(unsigned int, f);
  u += 0x7FFFu + ((u >> 16) & 1u);
  return (unsigned short)(u >> 16);
}

__device__ __forceinline__ void gld16(const void* g, void* l) {
  __builtin_amdgcn_global_load_lds((const __attribute__((address_space(1))) void*)g,
                                   (__attribute__((address_space(3))) void*)l, 16, 0, 0);
}

__device__ __forceinline__ unsigned int cvtpk(float lo, float hi) {
  unsigned int r;
  asm("v_cvt_pk_bf16_f32 %0, %1, %2" : "=v"(r) : "v"(lo), "v"(hi));
  return r;
}

__device__ __forceinline__ void pl32swap(unsigned int& a, unsigned int& b) {
  asm volatile("v_permlane32_swap_b32 %0, %1" : "+v"(a), "+v"(b));
}

// ---- convert x (fp32, [8192][2048], first 1024 cols) -> xb bf16 [8192][1024]
__global__ __launch_bounds__(256) void conv_x(const float* __restrict__ x,
                                              unsigned short* __restrict__ xb) {
  const size_t idx = ((size_t)blockIdx.x * 256 + threadIdx.x) * 8;
  const int m = (int)(idx >> 10);
  const int e = (int)(idx & 1023);
  const float4* s = (const float4*)(x + (size_t)m * 2048 + e);
  float4 a = s[0], b = s[1];
  u16x8 v;
  v[0]=f2bf(a.x); v[1]=f2bf(a.y); v[2]=f2bf(a.z); v[3]=f2bf(a.w);
  v[4]=f2bf(b.x); v[5]=f2bf(b.y); v[6]=f2bf(b.z); v[7]=f2bf(b.w);
  *(u16x8*)(xb + idx) = v;
}

// ---- pack Wq/Wk/Wv (fp32 [16][128][2048], first 64/1024 used) -> wb bf16 [3072][1024]
__global__ __launch_bounds__(256) void conv_w(const float* __restrict__ Wq,
                                              const float* __restrict__ Wk,
                                              const float* __restrict__ Wv,
                                              unsigned short* __restrict__ wb) {
  const size_t idx = ((size_t)blockIdx.x * 256 + threadIdx.x) * 8;
  const int n = (int)(idx >> 10);
  const int e = (int)(idx & 1023);
  const int mat = n >> 10, hh = (n >> 6) & 15, d = n & 63;
  const float* W = (mat == 0) ? Wq : ((mat == 1) ? Wk : Wv);
  const float4* s = (const float4*)(W + ((size_t)hh * 128 + d) * 2048 + e);
  float4 a = s[0], b = s[1];
  u16x8 v;
  v[0]=f2bf(a.x); v[1]=f2bf(a.y); v[2]=f2bf(a.z); v[3]=f2bf(a.w);
  v[4]=f2bf(b.x); v[5]=f2bf(b.y); v[6]=f2bf(b.z); v[7]=f2bf(b.w);
  *(u16x8*)(wb + idx) = v;
}

// ---- GEMM: [8192 x 1024] (xb) x [3072 x 1024]^T (wb) -> Q,K [b,h,t,64] bf16, Vt [b,h,64,t] bf16
__global__ __launch_bounds__(256) void qkv_gemm(const unsigned short* __restrict__ xb,
                                                const unsigned short* __restrict__ wb,
                                                unsigned short* __restrict__ Q,
                                                unsigned short* __restrict__ Kt,
                                                unsigned short* __restrict__ Vt) {
  __shared__ unsigned short As[128 * 64];
  __shared__ unsigned short Bs[128 * 64];
  const int tid = threadIdx.x;
  const int w = tid >> 6, lane = tid & 63, g = lane >> 4, c = lane & 15;
  const int m0 = blockIdx.x * 128;
  const int n0 = blockIdx.y * 128;

  f32x4 acc[2][8];
#pragma unroll
  for (int mi = 0; mi < 2; ++mi)
#pragma unroll
    for (int ni = 0; ni < 8; ++ni) acc[mi][ni] = (f32x4){0.f, 0.f, 0.f, 0.f};

  for (int kt = 0; kt < 16; ++kt) {
    const int k0 = kt * 64;
#pragma unroll
    for (int it = 0; it < 4; ++it) {
      int o = (it * 256 + tid) * 16;           // byte offset in 16KB tile
      int r = o >> 7, c2 = o & 127;
      int c2s = c2 ^ ((r & 7) << 4);           // inverse-swizzled source
      gld16(xb + ((size_t)(m0 + r) * 1024 + k0 + (c2s >> 1)), (char*)As + o);
      gld16(wb + ((size_t)(n0 + r) * 1024 + k0 + (c2s >> 1)), (char*)Bs + o);
    }
    __syncthreads();
#pragma unroll
    for (int kk = 0; kk < 2; ++kk) {
      bf16x8 af[2], bfr[8];
#pragma unroll
      for (int mi = 0; mi < 2; ++mi) {
        int r = w * 32 + mi * 16 + c;
        int c2s = (kk * 64 + g * 16) ^ ((r & 7) << 4);
        af[mi] = *(const bf16x8*)&As[r * 64 + (c2s >> 1)];
      }
#pragma unroll
      for (int ni = 0; ni < 8; ++ni) {
        int r = ni * 16 + c;
        int c2s = (kk * 64 + g * 16) ^ ((r & 7) << 4);
        bfr[ni] = *(const bf16x8*)&Bs[r * 64 + (c2s >> 1)];
      }
#pragma unroll
      for (int mi = 0; mi < 2; ++mi)
#pragma unroll
        for (int ni = 0; ni < 8; ++ni)
          acc[mi][ni] = __builtin_amdgcn_mfma_f32_16x16x32_bf16(af[mi], bfr[ni], acc[mi][ni], 0, 0, 0);
    }
    __syncthreads();
  }

  // epilogue: C[row=(lane>>4)*4+i, col=lane&15]
#pragma unroll
  for (int mi = 0; mi < 2; ++mi) {
    const int row_l = w * 32 + mi * 16 + g * 4;
#pragma unroll
    for (int i = 0; i < 4; ++i) {
      const int m = m0 + row_l + i;
      const int b = m >> 11, t = m & 2047;
#pragma unroll
      for (int ni = 0; ni < 8; ++ni) {
        const int n = n0 + ni * 16 + c;
        const int mat = n >> 10, hh = (n >> 6) & 15, d = n & 63;
        const unsigned short v = f2bf(acc[mi][ni][i]);
        const size_t bh = (size_t)(b * 16 + hh);
        if (mat == 0)      Q [(bh * TT + t) * 64 + d] = v;
        else if (mat == 1) Kt[(bh * TT + t) * 64 + d] = v;
        else               Vt[(bh * 64 + d) * TT + t] = v;
      }
    }
  }
}

// ---- zero pad cols 1024..2047 of out (runs after gemm consumed xb scratch)
__global__ __launch_bounds__(256) void zero_pad(float* __restrict__ out) {
  const int idx = blockIdx.x * 256 + threadIdx.x;     // 8192*256
  const int row = idx >> 8, c4 = idx & 255;
  *((float4*)(out + (size_t)row * 2048 + 1024) + c4) = make_float4(0.f, 0.f, 0.f, 0.f);
}

// ---- flash attention, causal. 4 waves/block, 32 q-rows/wave, block shares a
// 64-k double-buffered LDS stream for K and Vt (T3 2-phase + T2 swizzle).
// Swapped layout: S^T = mfma(K, Q); lane owns q = lane&31. O^T = mfma(Vt, P^T).
__global__ __launch_bounds__(256) void attn4(const unsigned short* __restrict__ Q,
                                             const unsigned short* __restrict__ K,
                                             const unsigned short* __restrict__ Vt,
                                             float* __restrict__ out) {
  __shared__ unsigned short Ks[2][4096];   // [buf][krow*64 + d]  (swizzled), 8KB/buf
  __shared__ unsigned short Vs[2][4096];   // [buf][d*64 + t]     (swizzled), 8KB/buf
  const int blk = blockIdx.x;              // 1024 = 64 bh * 16 q-blocks
  const int bh = blk & 63;                 // bh%8 -> XCD L2 affinity
  const int qi = 15 - (blk >> 6);          // heavy (high-q) blocks first
  const int b = bh >> 4, h = bh & 15;
  const int tid = threadIdx.x;
  const int w = tid >> 6, lane = tid & 63;
  const int ql = lane & 31;
  const int hi = lane >> 5, hi8 = hi * 8;
  const int q0 = qi * 128;
  const int qw = q0 + w * 32;              // this wave's q-tile base
  const int q = qw + ql;
  const unsigned short* Qp = Q  + (size_t)bh * TT * 64;
  const unsigned short* Kp = K  + (size_t)bh * TT * 64;
  const unsigned short* Vp = Vt + (size_t)bh * 64 * TT;

  bf16x8 qf0, qf1, qf2, qf3;
  {
    const unsigned short* qa = Qp + (size_t)q * 64 + hi8;
    qf0 = *(const bf16x8*)(qa);
    qf1 = *(const bf16x8*)(qa + 16);
    qf2 = *(const bf16x8*)(qa + 32);
    qf3 = *(const bf16x8*)(qa + 48);
  }

  f32x16 o0, o1;
#pragma unroll
  for (int r = 0; r < 16; ++r) { o0[r] = 0.f; o1[r] = 0.f; }
  float m = -3.0e38f, l = 0.f;
  const float c2 = 0.125f * 1.44269504f;

  const int nt = qi * 2 + 2;               // 64-k tiles covering [0, q0+128)

  // STAGE tile t into buffer buf: K tile is 8KB contiguous; Vt tile strided.
  // Linear LDS dest + inverse-swizzled global source (both-sides rule).
  auto STAGE = [&](int t, int buf) {
#pragma unroll
    for (int it = 0; it < 2; ++it) {
      const int o = (it * 256 + tid) * 16;       // byte offset 0..8191
      const int r = o >> 7, c = o & 127;
      const int cs = c ^ ((r & 7) << 4);
      gld16(Kp + (size_t)t * 4096 + r * 64 + (cs >> 1), (char*)&Ks[buf][0] + o);
      gld16(Vp + (size_t)r * 2048 + t * 64 + (cs >> 1), (char*)&Vs[buf][0] + o);
    }
  };

  STAGE(0, 0);
  asm volatile("s_waitcnt vmcnt(0)" ::: "memory");
  __syncthreads();

  int cur = 0;
  for (int t = 0; t < nt; ++t) {
    if (t + 1 < nt) STAGE(t + 1, cur ^ 1);

#pragma unroll
    for (int s = 0; s < 2; ++s) {
      const int ks32 = t * 64 + s * 32;
      if (ks32 <= qw) {
        // --- K fragments from LDS (A operand: rows = k, 8 d-elems per frag)
        const int krow = s * 32 + ql;
        const char* kb = (const char*)&Ks[cur][krow * 64];
        const int ksz = (krow & 7) << 4;
        bf16x8 kf0 = *(const bf16x8*)(kb + ((0  + hi * 16) ^ ksz));
        bf16x8 kf1 = *(const bf16x8*)(kb + ((32 + hi * 16) ^ ksz));
        bf16x8 kf2 = *(const bf16x8*)(kb + ((64 + hi * 16) ^ ksz));
        bf16x8 kf3 = *(const bf16x8*)(kb + ((96 + hi * 16) ^ ksz));
        // --- V fragments from LDS (A operand: rows = d, 8 t-elems per frag)
        const int vsz = (ql & 7) << 4;
        const char* vb0 = (const char*)&Vs[cur][ql * 64];
        const char* vb1 = (const char*)&Vs[cur][(ql + 32) * 64];
        bf16x8 vf0 = *(const bf16x8*)(vb0 + ((s * 64 + 0  + hi * 16) ^ vsz));
        bf16x8 vf1 = *(const bf16x8*)(vb0 + ((s * 64 + 32 + hi * 16) ^ vsz));
        bf16x8 vf2 = *(const bf16x8*)(vb1 + ((s * 64 + 0  + hi * 16) ^ vsz));
        bf16x8 vf3 = *(const bf16x8*)(vb1 + ((s * 64 + 32 + hi * 16) ^ vsz));

        // --- QK^T swapped: st[r] = S^T[k=(r&3)+8*(r>>2)+4*hi][q=ql]
        f32x16 st;
#pragma unroll
        for (int r = 0; r < 16; ++r) st[r] = 0.f;
        __builtin_amdgcn_s_setprio(1);
        st = __builtin_amdgcn_mfma_f32_32x32x16_bf16(kf0, qf0, st, 0, 0, 0);
        st = __builtin_amdgcn_mfma_f32_32x32x16_bf16(kf1, qf1, st, 0, 0, 0);
        st = __builtin_amdgcn_mfma_f32_32x32x16_bf16(kf2, qf2, st, 0, 0, 0);
        st = __builtin_amdgcn_mfma_f32_32x32x16_bf16(kf3, qf3, st, 0, 0, 0);
        __builtin_amdgcn_s_setprio(0);

        if (ks32 == qw) {                  // diagonal sub-tile: causal mask
#pragma unroll
          for (int r = 0; r < 16; ++r) {
            const int krw = (r & 3) + 8 * (r >> 2) + 4 * hi;
            if (krw > ql) st[r] = -3.0e38f;
          }
        }

        // --- online softmax, in-register (lane owns q=ql)
        float t0 = fmaxf(st[0], st[1]),  t1 = fmaxf(st[2], st[3]);
        float t2 = fmaxf(st[4], st[5]),  t3 = fmaxf(st[6], st[7]);
        float t4 = fmaxf(st[8], st[9]),  t5 = fmaxf(st[10], st[11]);
        float t6 = fmaxf(st[12], st[13]), t7 = fmaxf(st[14], st[15]);
        t0 = fmaxf(t0, t1); t2 = fmaxf(t2, t3); t4 = fmaxf(t4, t5); t6 = fmaxf(t6, t7);
        float pm = fmaxf(fmaxf(t0, t2), fmaxf(t4, t6));
        pm = fmaxf(pm, __shfl_xor(pm, 32));
        if (!__all(pm - m <= 44.36f)) {    // defer-max (THR=8 in exp units)
          const float mnew = fmaxf(m, pm);
          const float alpha = __builtin_amdgcn_exp2f((m - mnew) * c2);
          m = mnew;
          l *= alpha;
#pragma unroll
          for (int r = 0; r < 16; ++r) { o0[r] *= alpha; o1[r] *= alpha; }
        }
        float p[16];
        float rs = 0.f;
#pragma unroll
        for (int r = 0; r < 16; ++r) {
          p[r] = __builtin_amdgcn_exp2f((st[r] - m) * c2);
          rs += p[r];
        }
        rs += __shfl_xor(rs, 32);
        l += rs;

        // --- pack P^T into B-fragments (cvt_pk + permlane32_swap)
        unsigned int a0 = cvtpk(p[0], p[1]),  a1 = cvtpk(p[2], p[3]);
        unsigned int b0 = cvtpk(p[4], p[5]),  b1 = cvtpk(p[6], p[7]);
        pl32swap(a0, b0); pl32swap(a1, b1);
        unsigned int cc0 = cvtpk(p[8], p[9]),  cc1 = cvtpk(p[10], p[11]);
        unsigned int dd0 = cvtpk(p[12], p[13]), dd1 = cvtpk(p[14], p[15]);
        pl32swap(cc0, dd0); pl32swap(cc1, dd1);
        u32x4 pw0 = {a0, a1, b0, b1};
        u32x4 pw1 = {cc0, cc1, dd0, dd1};
        bf16x8 pf0 = __builtin_bit_cast(bf16x8, pw0);
        bf16x8 pf1 = __builtin_bit_cast(bf16x8, pw1);

        // --- PV swapped: O^T[d][q] += V^T[d][k] * P^T[k][q]
        __builtin_amdgcn_s_setprio(1);
        o0 = __builtin_amdgcn_mfma_f32_32x32x16_bf16(vf0, pf0, o0, 0, 0, 0);
        o0 = __builtin_amdgcn_mfma_f32_32x32x16_bf16(vf1, pf1, o0, 0, 0, 0);
        o1 = __builtin_amdgcn_mfma_f32_32x32x16_bf16(vf2, pf0, o1, 0, 0, 0);
        o1 = __builtin_amdgcn_mfma_f32_32x32x16_bf16(vf3, pf1, o1, 0, 0, 0);
        __builtin_amdgcn_s_setprio(0);
      }
    }

    asm volatile("s_waitcnt vmcnt(0)" ::: "memory");
    __syncthreads();
    cur ^= 1;
  }

  const float inv = 1.f / l;
  float* ob = out + ((size_t)b * TT + q) * 2048 + h * 64;
#pragma unroll
  for (int r = 0; r < 16; ++r) {
    const int row = (r & 3) + 8 * (r >> 2) + 4 * hi;
    ob[row]      = o0[r] * inv;
    ob[32 + row] = o1[r] * inv;
  }
}

extern "C" void kernel_launch(void* const* d_in, const int* in_sizes, int n_in,
                              void* d_out, int out_size, void* d_ws, size_t ws_size,
                              hipStream_t stream) {
  const float* x  = (const float*)d_in[0];
  const float* Wq = (const float*)d_in[1];
  const float* Wk = (const float*)d_in[2];
  const float* Wv = (const float*)d_in[3];

  unsigned short* wsp = (unsigned short*)d_ws;
  unsigned short* Q   = wsp;                       // 8,388,608 bf16
  unsigned short* Kt  = wsp + (size_t)8388608;
  unsigned short* Vt  = wsp + (size_t)16777216;

  // d_out doubles as scratch for bf16-converted inputs; fully overwritten later.
  unsigned short* xb = (unsigned short*)d_out;                          // 16.8 MB
  unsigned short* wb = (unsigned short*)((char*)d_out + 33554432);      // 6.3 MB
  float* out = (float*)d_out;

  conv_x<<<4096, 256, 0, stream>>>(x, xb);
  conv_w<<<1536, 256, 0, stream>>>(Wq, Wk, Wv, wb);
  qkv_gemm<<<dim3(64, 24), 256, 0, stream>>>(xb, wb, Q, Kt, Vt);
  zero_pad<<<8192, 256, 0, stream>>>(out);
  attn4<<<1024, 256, 0, stream>>>(Q, Kt, Vt, out);
}

// Round 5
// 157.668 us; speedup vs baseline: 3.4512x; 1.1620x over previous
//
#include <hip/hip_runtime.h>

typedef __attribute__((ext_vector_type(8))) short bf16x8;
typedef __attribute__((ext_vector_type(4))) float f32x4;
typedef __attribute__((ext_vector_type(16))) float f32x16;
typedef __attribute__((ext_vector_type(8))) unsigned short u16x8;
typedef __attribute__((ext_vector_type(4))) unsigned int u32x4;

#define TT 2048

__device__ __forceinline__ unsigned short f2bf(float f) {
  unsigned int u = __builtin_bit_cast(unsigned int, f);
  u += 0x7FFFu + ((u >> 16) & 1u);
  return (unsigned short)(u >> 16);
}

__device__ __forceinline__ void gld16(const void* g, void* l) {
  __builtin_amdgcn_global_load_lds((const __attribute__((address_space(1))) void*)g,
                                   (__attribute__((address_space(3))) void*)l, 16, 0, 0);
}

__device__ __forceinline__ unsigned int cvtpk(float lo, float hi) {
  unsigned int r;
  asm("v_cvt_pk_bf16_f32 %0, %1, %2" : "=v"(r) : "v"(lo), "v"(hi));
  return r;
}

__device__ __forceinline__ void pl32swap(unsigned int& a, unsigned int& b) {
  asm volatile("v_permlane32_swap_b32 %0, %1" : "+v"(a), "+v"(b));
}

// ---- convert x (fp32, [8192][2048], first 1024 cols) -> xb bf16 [8192][1024]
__global__ __launch_bounds__(256) void conv_x(const float* __restrict__ x,
                                              unsigned short* __restrict__ xb) {
  const size_t idx = ((size_t)blockIdx.x * 256 + threadIdx.x) * 8;
  const int m = (int)(idx >> 10);
  const int e = (int)(idx & 1023);
  const float4* s = (const float4*)(x + (size_t)m * 2048 + e);
  float4 a = s[0], b = s[1];
  u16x8 v;
  v[0]=f2bf(a.x); v[1]=f2bf(a.y); v[2]=f2bf(a.z); v[3]=f2bf(a.w);
  v[4]=f2bf(b.x); v[5]=f2bf(b.y); v[6]=f2bf(b.z); v[7]=f2bf(b.w);
  *(u16x8*)(xb + idx) = v;
}

// ---- pack Wq/Wk/Wv (fp32 [16][128][2048], first 64/1024 used) -> wb bf16 [3072][1024]
__global__ __launch_bounds__(256) void conv_w(const float* __restrict__ Wq,
                                              const float* __restrict__ Wk,
                                              const float* __restrict__ Wv,
                                              unsigned short* __restrict__ wb) {
  const size_t idx = ((size_t)blockIdx.x * 256 + threadIdx.x) * 8;
  const int n = (int)(idx >> 10);
  const int e = (int)(idx & 1023);
  const int mat = n >> 10, hh = (n >> 6) & 15, d = n & 63;
  const float* W = (mat == 0) ? Wq : ((mat == 1) ? Wk : Wv);
  const float4* s = (const float4*)(W + ((size_t)hh * 128 + d) * 2048 + e);
  float4 a = s[0], b = s[1];
  u16x8 v;
  v[0]=f2bf(a.x); v[1]=f2bf(a.y); v[2]=f2bf(a.z); v[3]=f2bf(a.w);
  v[4]=f2bf(b.x); v[5]=f2bf(b.y); v[6]=f2bf(b.z); v[7]=f2bf(b.w);
  *(u16x8*)(wb + idx) = v;
}

// ---- GEMM: [8192 x 1024] (xb) x [3072 x 1024]^T (wb) -> Q,K [b,h,t,64], Vt [b,h,64,t]
// BM=128 BN=256 BK=64, 512 thr (8 waves, 2Mx4N, wave tile 64x64), dbuf LDS +
// counted vmcnt pipeline (T3/T4), raw s_barrier (no vmcnt(0) drain), T2 swizzle.
__global__ __launch_bounds__(512) void qkv_gemm2(const unsigned short* __restrict__ xb,
                                                 const unsigned short* __restrict__ wb,
                                                 unsigned short* __restrict__ Q,
                                                 unsigned short* __restrict__ Kt,
                                                 unsigned short* __restrict__ Vt) {
  __shared__ unsigned short As[2][128 * 64];   // 32 KB
  __shared__ unsigned short Bs[2][256 * 64];   // 64 KB
  const int tid = threadIdx.x;
  const int w = tid >> 6, lane = tid & 63, g = lane >> 4, c = lane & 15;
  const int wm = w >> 2, wn = w & 3;
  const int m0 = blockIdx.x * 128;
  const int n0 = blockIdx.y * 256;

  f32x4 acc[4][4];
#pragma unroll
  for (int mi = 0; mi < 4; ++mi)
#pragma unroll
    for (int ni = 0; ni < 4; ++ni) acc[mi][ni] = (f32x4){0.f, 0.f, 0.f, 0.f};

  // 6 gld16 per thread per tile (A:2, B:4). Linear LDS dest + inv-swizzled src.
  auto STAGE = [&](int t, int buf) {
    const int k0 = t * 64;
#pragma unroll
    for (int it = 0; it < 2; ++it) {
      const int o = (it * 512 + tid) * 16;
      const int r = o >> 7, cc = o & 127;
      const int cs = cc ^ ((r & 7) << 4);
      gld16(xb + ((size_t)(m0 + r) << 10) + k0 + (cs >> 1), (char*)&As[buf][0] + o);
    }
#pragma unroll
    for (int it = 0; it < 4; ++it) {
      const int o = (it * 512 + tid) * 16;
      const int r = o >> 7, cc = o & 127;
      const int cs = cc ^ ((r & 7) << 4);
      gld16(wb + ((size_t)(n0 + r) << 10) + k0 + (cs >> 1), (char*)&Bs[buf][0] + o);
    }
  };

  STAGE(0, 0);
  STAGE(1, 1);
  asm volatile("s_waitcnt vmcnt(6)" ::: "memory");   // tile 0 landed; tile 1 in flight
  __builtin_amdgcn_s_barrier();

  for (int t = 0; t < 16; ++t) {
    const int cur = t & 1;
#pragma unroll
    for (int kk = 0; kk < 2; ++kk) {
      bf16x8 af[4], bfv[4];
#pragma unroll
      for (int mi = 0; mi < 4; ++mi) {
        const int r = wm * 64 + mi * 16 + c;
        const int cs = (kk * 64 + g * 16) ^ ((r & 7) << 4);
        af[mi] = *(const bf16x8*)((const char*)&As[cur][r * 64] + cs);
      }
#pragma unroll
      for (int ni = 0; ni < 4; ++ni) {
        const int r = wn * 64 + ni * 16 + c;
        const int cs = (kk * 64 + g * 16) ^ ((r & 7) << 4);
        bfv[ni] = *(const bf16x8*)((const char*)&Bs[cur][r * 64] + cs);
      }
      __builtin_amdgcn_s_setprio(1);
#pragma unroll
      for (int mi = 0; mi < 4; ++mi)
#pragma unroll
        for (int ni = 0; ni < 4; ++ni)
          acc[mi][ni] = __builtin_amdgcn_mfma_f32_16x16x32_bf16(af[mi], bfv[ni], acc[mi][ni], 0, 0, 0);
      __builtin_amdgcn_s_setprio(0);
    }
    __builtin_amdgcn_s_barrier();        // all waves done reading buf cur
    if (t + 2 < 16) {
      STAGE(t + 2, cur);                 // overwrite cur; 6 loads in flight
      asm volatile("s_waitcnt vmcnt(6)" ::: "memory");   // tile t+1 landed
      __builtin_amdgcn_s_barrier();
    } else if (t + 1 < 16) {
      asm volatile("s_waitcnt vmcnt(0)" ::: "memory");
      __builtin_amdgcn_s_barrier();
    }
  }

  // epilogue: C[row=(lane>>4)*4+i, col=lane&15]; mat uniform per block (BN=256)
#pragma unroll
  for (int mi = 0; mi < 4; ++mi) {
    const int row_l = wm * 64 + mi * 16 + g * 4;
#pragma unroll
    for (int i = 0; i < 4; ++i) {
      const int m = m0 + row_l + i;
      const int b = m >> 11, tt = m & 2047;
#pragma unroll
      for (int ni = 0; ni < 4; ++ni) {
        const int n = n0 + wn * 64 + ni * 16 + c;
        const int mat = n >> 10, hh = (n >> 6) & 15, d = n & 63;
        const unsigned short v = f2bf(acc[mi][ni][i]);
        const size_t bh = (size_t)(b * 16 + hh);
        if (mat == 0)      Q [(bh * TT + tt) * 64 + d] = v;
        else if (mat == 1) Kt[(bh * TT + tt) * 64 + d] = v;
        else               Vt[(bh * 64 + d) * TT + tt] = v;
      }
    }
  }
}

// ---- flash attention, causal. 4 waves/block, 32 q-rows/wave, block shares a
// 64-k double-buffered LDS stream for K and Vt (T3 2-phase + T2 swizzle).
// Swapped layout: S^T = mfma(K, Q); lane owns q = lane&31. O^T = mfma(Vt, P^T).
// Also zeroes this (b, q-rows, h) slice of the pad columns.
__global__ __launch_bounds__(256) void attn4(const unsigned short* __restrict__ Q,
                                             const unsigned short* __restrict__ K,
                                             const unsigned short* __restrict__ Vt,
                                             float* __restrict__ out) {
  __shared__ unsigned short Ks[2][4096];   // [buf][krow*64 + d]  (swizzled), 8KB/buf
  __shared__ unsigned short Vs[2][4096];   // [buf][d*64 + t]     (swizzled), 8KB/buf
  const int blk = blockIdx.x;              // 1024 = 64 bh * 16 q-blocks
  const int bh = blk & 63;                 // bh%8 -> XCD L2 affinity
  const int qi = 15 - (blk >> 6);          // heavy (high-q) blocks first
  const int b = bh >> 4, h = bh & 15;
  const int tid = threadIdx.x;
  const int w = tid >> 6, lane = tid & 63;
  const int ql = lane & 31;
  const int hi = lane >> 5, hi8 = hi * 8;
  const int q0 = qi * 128;
  const int qw = q0 + w * 32;              // this wave's q-tile base
  const int q = qw + ql;
  const unsigned short* Qp = Q  + (size_t)bh * TT * 64;
  const unsigned short* Kp = K  + (size_t)bh * TT * 64;
  const unsigned short* Vp = Vt + (size_t)bh * 64 * TT;

  bf16x8 qf0, qf1, qf2, qf3;
  {
    const unsigned short* qa = Qp + (size_t)q * 64 + hi8;
    qf0 = *(const bf16x8*)(qa);
    qf1 = *(const bf16x8*)(qa + 16);
    qf2 = *(const bf16x8*)(qa + 32);
    qf3 = *(const bf16x8*)(qa + 48);
  }

  f32x16 o0, o1;
#pragma unroll
  for (int r = 0; r < 16; ++r) { o0[r] = 0.f; o1[r] = 0.f; }
  float m = -3.0e38f, l = 0.f;
  const float c2 = 0.125f * 1.44269504f;

  const int nt = qi * 2 + 2;               // 64-k tiles covering [0, q0+128)

  auto STAGE = [&](int t, int buf) {
#pragma unroll
    for (int it = 0; it < 2; ++it) {
      const int o = (it * 256 + tid) * 16;       // byte offset 0..8191
      const int r = o >> 7, c = o & 127;
      const int cs = c ^ ((r & 7) << 4);
      gld16(Kp + (size_t)t * 4096 + r * 64 + (cs >> 1), (char*)&Ks[buf][0] + o);
      gld16(Vp + (size_t)r * 2048 + t * 64 + (cs >> 1), (char*)&Vs[buf][0] + o);
    }
  };

  STAGE(0, 0);
  asm volatile("s_waitcnt vmcnt(0)" ::: "memory");
  __syncthreads();

  int cur = 0;
  for (int t = 0; t < nt; ++t) {
    if (t + 1 < nt) STAGE(t + 1, cur ^ 1);

#pragma unroll
    for (int s = 0; s < 2; ++s) {
      const int ks32 = t * 64 + s * 32;
      if (ks32 <= qw) {
        // --- K fragments from LDS (A operand: rows = k, 8 d-elems per frag)
        const int krow = s * 32 + ql;
        const char* kb = (const char*)&Ks[cur][krow * 64];
        const int ksz = (krow & 7) << 4;
        bf16x8 kf0 = *(const bf16x8*)(kb + ((0  + hi * 16) ^ ksz));
        bf16x8 kf1 = *(const bf16x8*)(kb + ((32 + hi * 16) ^ ksz));
        bf16x8 kf2 = *(const bf16x8*)(kb + ((64 + hi * 16) ^ ksz));
        bf16x8 kf3 = *(const bf16x8*)(kb + ((96 + hi * 16) ^ ksz));
        // --- V fragments from LDS (A operand: rows = d, 8 t-elems per frag)
        const int vsz = (ql & 7) << 4;
        const char* vb0 = (const char*)&Vs[cur][ql * 64];
        const char* vb1 = (const char*)&Vs[cur][(ql + 32) * 64];
        bf16x8 vf0 = *(const bf16x8*)(vb0 + ((s * 64 + 0  + hi * 16) ^ vsz));
        bf16x8 vf1 = *(const bf16x8*)(vb0 + ((s * 64 + 32 + hi * 16) ^ vsz));
        bf16x8 vf2 = *(const bf16x8*)(vb1 + ((s * 64 + 0  + hi * 16) ^ vsz));
        bf16x8 vf3 = *(const bf16x8*)(vb1 + ((s * 64 + 32 + hi * 16) ^ vsz));

        // --- QK^T swapped: st[r] = S^T[k=(r&3)+8*(r>>2)+4*hi][q=ql]
        f32x16 st;
#pragma unroll
        for (int r = 0; r < 16; ++r) st[r] = 0.f;
        __builtin_amdgcn_s_setprio(1);
        st = __builtin_amdgcn_mfma_f32_32x32x16_bf16(kf0, qf0, st, 0, 0, 0);
        st = __builtin_amdgcn_mfma_f32_32x32x16_bf16(kf1, qf1, st, 0, 0, 0);
        st = __builtin_amdgcn_mfma_f32_32x32x16_bf16(kf2, qf2, st, 0, 0, 0);
        st = __builtin_amdgcn_mfma_f32_32x32x16_bf16(kf3, qf3, st, 0, 0, 0);
        __builtin_amdgcn_s_setprio(0);

        if (ks32 == qw) {                  // diagonal sub-tile: causal mask
#pragma unroll
          for (int r = 0; r < 16; ++r) {
            const int krw = (r & 3) + 8 * (r >> 2) + 4 * hi;
            if (krw > ql) st[r] = -3.0e38f;
          }
        }

        // --- online softmax, in-register (lane owns q=ql)
        float t0 = fmaxf(st[0], st[1]),  t1 = fmaxf(st[2], st[3]);
        float t2 = fmaxf(st[4], st[5]),  t3 = fmaxf(st[6], st[7]);
        float t4 = fmaxf(st[8], st[9]),  t5 = fmaxf(st[10], st[11]);
        float t6 = fmaxf(st[12], st[13]), t7 = fmaxf(st[14], st[15]);
        t0 = fmaxf(t0, t1); t2 = fmaxf(t2, t3); t4 = fmaxf(t4, t5); t6 = fmaxf(t6, t7);
        float pm = fmaxf(fmaxf(t0, t2), fmaxf(t4, t6));
        pm = fmaxf(pm, __shfl_xor(pm, 32));
        if (!__all(pm - m <= 44.36f)) {    // defer-max (THR=8 in exp units)
          const float mnew = fmaxf(m, pm);
          const float alpha = __builtin_amdgcn_exp2f((m - mnew) * c2);
          m = mnew;
          l *= alpha;
#pragma unroll
          for (int r = 0; r < 16; ++r) { o0[r] *= alpha; o1[r] *= alpha; }
        }
        float p[16];
        float rs = 0.f;
#pragma unroll
        for (int r = 0; r < 16; ++r) {
          p[r] = __builtin_amdgcn_exp2f((st[r] - m) * c2);
          rs += p[r];
        }
        rs += __shfl_xor(rs, 32);
        l += rs;

        // --- pack P^T into B-fragments (cvt_pk + permlane32_swap)
        unsigned int a0 = cvtpk(p[0], p[1]),  a1 = cvtpk(p[2], p[3]);
        unsigned int b0 = cvtpk(p[4], p[5]),  b1 = cvtpk(p[6], p[7]);
        pl32swap(a0, b0); pl32swap(a1, b1);
        unsigned int cc0 = cvtpk(p[8], p[9]),  cc1 = cvtpk(p[10], p[11]);
        unsigned int dd0 = cvtpk(p[12], p[13]), dd1 = cvtpk(p[14], p[15]);
        pl32swap(cc0, dd0); pl32swap(cc1, dd1);
        u32x4 pw0 = {a0, a1, b0, b1};
        u32x4 pw1 = {cc0, cc1, dd0, dd1};
        bf16x8 pf0 = __builtin_bit_cast(bf16x8, pw0);
        bf16x8 pf1 = __builtin_bit_cast(bf16x8, pw1);

        // --- PV swapped: O^T[d][q] += V^T[d][k] * P^T[k][q]
        __builtin_amdgcn_s_setprio(1);
        o0 = __builtin_amdgcn_mfma_f32_32x32x16_bf16(vf0, pf0, o0, 0, 0, 0);
        o0 = __builtin_amdgcn_mfma_f32_32x32x16_bf16(vf1, pf1, o0, 0, 0, 0);
        o1 = __builtin_amdgcn_mfma_f32_32x32x16_bf16(vf2, pf0, o1, 0, 0, 0);
        o1 = __builtin_amdgcn_mfma_f32_32x32x16_bf16(vf3, pf1, o1, 0, 0, 0);
        __builtin_amdgcn_s_setprio(0);
      }
    }

    asm volatile("s_waitcnt vmcnt(0)" ::: "memory");
    __syncthreads();
    cur ^= 1;
  }

  const float inv = 1.f / l;
  float* ob = out + ((size_t)b * TT + q) * 2048 + h * 64;
#pragma unroll
  for (int r = 0; r < 16; ++r) {
    const int row = (r & 3) + 8 * (r >> 2) + 4 * hi;
    ob[row]      = o0[r] * inv;
    ob[32 + row] = o1[r] * inv;
  }

  // zero the pad slice: rows q0..q0+127, cols 1024+h*64 .. +63
  const float4 z = make_float4(0.f, 0.f, 0.f, 0.f);
#pragma unroll
  for (int it = 0; it < 8; ++it) {
    const int idx = it * 256 + tid;      // 0..2047
    const int r = idx >> 4, c4 = idx & 15;
    *((float4*)(out + ((size_t)b * TT + q0 + r) * 2048 + 1024 + h * 64) + c4) = z;
  }
}

extern "C" void kernel_launch(void* const* d_in, const int* in_sizes, int n_in,
                              void* d_out, int out_size, void* d_ws, size_t ws_size,
                              hipStream_t stream) {
  const float* x  = (const float*)d_in[0];
  const float* Wq = (const float*)d_in[1];
  const float* Wk = (const float*)d_in[2];
  const float* Wv = (const float*)d_in[3];

  unsigned short* wsp = (unsigned short*)d_ws;
  unsigned short* Q   = wsp;                       // 8,388,608 bf16
  unsigned short* Kt  = wsp + (size_t)8388608;
  unsigned short* Vt  = wsp + (size_t)16777216;

  // d_out doubles as scratch for bf16-converted inputs; fully overwritten later.
  unsigned short* xb = (unsigned short*)d_out;                          // 16.8 MB
  unsigned short* wb = (unsigned short*)((char*)d_out + 33554432);      // 6.3 MB
  float* out = (float*)d_out;

  conv_x<<<4096, 256, 0, stream>>>(x, xb);
  conv_w<<<1536, 256, 0, stream>>>(Wq, Wk, Wv, wb);
  qkv_gemm2<<<dim3(64, 12), 512, 0, stream>>>(xb, wb, Q, Kt, Vt);
  attn4<<<1024, 256, 0, stream>>>(Q, Kt, Vt, out);
}